// Round 3
// baseline (768.706 us; speedup 1.0000x reference)
//
#include <hip/hip_runtime.h>

typedef short s16x8 __attribute__((ext_vector_type(8)));
typedef float f32x4 __attribute__((ext_vector_type(4)));
typedef unsigned short u16;

static __device__ __forceinline__ f32x4 mfma16(s16x8 a, s16x8 b, f32x4 c) {
  return __builtin_amdgcn_mfma_f32_16x16x32_bf16(a, b, c, 0, 0, 0);
}

// fp32 -> bf16 round-to-nearest-even
static __device__ __forceinline__ u16 f2b(float f) {
  union { float f; unsigned int u; } v; v.f = f;
  unsigned int u = v.u;
  return (u16)((u + 0x7fffu + ((u >> 16) & 1u)) >> 16);
}
static __device__ __forceinline__ float b2f(u16 h) {
  union { float f; unsigned int u; } v; v.u = ((unsigned int)h) << 16;
  return v.f;
}

// async global->LDS, 16B per lane; LDS dest = wave-uniform base + lane*16
static __device__ __forceinline__ void gld_lds16(const void* g, void* l) {
  __builtin_amdgcn_global_load_lds(
      (const __attribute__((address_space(1))) void*)g,
      (__attribute__((address_space(3))) void*)l, 16, 0, 0);
}

// ---------------------------------------------------------------------------
// Generic small GEMM: C[M][N] = A[M][K] @ B[K][N]  (fp32 in, bf16 staged, fp32 acc)
// MODE 0: store bf16 C row-major       MODE 1: store fp32 C TRANSPOSED
// MODE 2: store fp32 C row-major += bias[n]   MODE 3: store fp32 C row-major
// blockIdx.z batching via za/zb/zc element offsets. M%64==0,N%64==0,K%32==0.
// ---------------------------------------------------------------------------
template<int MODE>
__global__ __launch_bounds__(256)
void gemm_pre(const float* __restrict__ A, const float* __restrict__ B,
              void* __restrict__ Cout, const float* __restrict__ bias,
              int M, int N, int K, int lda, int ldb, int ldc,
              size_t za, size_t zb, size_t zc) {
  __shared__ u16 As[64][40];
  __shared__ u16 BsT[64][40];
  A += za * blockIdx.z;  B += zb * blockIdx.z;
  const size_t coff = zc * blockIdx.z;
  const int m0 = blockIdx.y << 6, n0 = blockIdx.x << 6;
  const int tid = threadIdx.x;
  const int wave = tid >> 6, lane = tid & 63;
  const int quad = lane >> 4, l16 = lane & 15;
  f32x4 acc[4] = {{0,0,0,0},{0,0,0,0},{0,0,0,0},{0,0,0,0}};
  for (int k0 = 0; k0 < K; k0 += 32) {
    __syncthreads();
    { // stage A tile 64x32
      const int r = tid >> 2, cs = (tid & 3) << 3;
      const float* ap = A + (size_t)(m0 + r) * lda + k0 + cs;
      float4 v0 = *(const float4*)ap, v1 = *(const float4*)(ap + 4);
      As[r][cs+0] = f2b(v0.x); As[r][cs+1] = f2b(v0.y);
      As[r][cs+2] = f2b(v0.z); As[r][cs+3] = f2b(v0.w);
      As[r][cs+4] = f2b(v1.x); As[r][cs+5] = f2b(v1.y);
      As[r][cs+6] = f2b(v1.z); As[r][cs+7] = f2b(v1.w);
    }
    { // stage B tile 32x64 transposed -> BsT[n][k]
      const int kk = tid >> 3, ns = (tid & 7) << 3;
      const float* bp = B + (size_t)(k0 + kk) * ldb + n0 + ns;
      float4 v0 = *(const float4*)bp, v1 = *(const float4*)(bp + 4);
      BsT[ns+0][kk] = f2b(v0.x); BsT[ns+1][kk] = f2b(v0.y);
      BsT[ns+2][kk] = f2b(v0.z); BsT[ns+3][kk] = f2b(v0.w);
      BsT[ns+4][kk] = f2b(v1.x); BsT[ns+5][kk] = f2b(v1.y);
      BsT[ns+6][kk] = f2b(v1.z); BsT[ns+7][kk] = f2b(v1.w);
    }
    __syncthreads();
    const s16x8 af = *(const s16x8*)&As[(wave << 4) + l16][quad << 3];
    #pragma unroll
    for (int nt = 0; nt < 4; nt++) {
      const s16x8 bfr = *(const s16x8*)&BsT[(nt << 4) + l16][quad << 3];
      acc[nt] = mfma16(af, bfr, acc[nt]);
    }
  }
  const int mrow = m0 + (wave << 4) + (quad << 2);
  #pragma unroll
  for (int nt = 0; nt < 4; nt++) {
    const int n = n0 + (nt << 4) + l16;
    float badd = 0.f;
    if (MODE == 2) badd = bias[n];
    #pragma unroll
    for (int r = 0; r < 4; r++) {
      float v = acc[nt][r] + badd;
      if (MODE == 0)      ((u16*)Cout)[coff + (size_t)(mrow + r) * ldc + n] = f2b(v);
      else if (MODE == 1) ((float*)Cout)[coff + (size_t)n * ldc + (mrow + r)] = v;
      else                ((float*)Cout)[coff + (size_t)(mrow + r) * ldc + n] = v;
    }
  }
}

// out[j] = sum_k A[j][k]*v[k] + c[j]
__global__ __launch_bounds__(256)
void bias_dot(const float* __restrict__ A, const float* __restrict__ v,
              const float* __restrict__ c, float* __restrict__ out,
              int M, int K) {
  int j = blockIdx.x * 256 + threadIdx.x;
  if (j >= M) return;
  const float* ar = A + (size_t)j * K;
  float acc = 0.f;
  for (int k = 0; k < K; k += 4) {
    float4 w = *(const float4*)(ar + k);
    acc += w.x * v[k] + w.y * v[k+1] + w.z * v[k+2] + w.w * v[k+3];
  }
  out[j] = acc + c[j];
}

// ---------------------------------------------------------------------------
// Phase 0: convert chunk_features fp32 [50000][768] -> bf16 [50048][768], pad=0
// ---------------------------------------------------------------------------
__global__ __launch_bounds__(256)
void convert_bf16(const float* __restrict__ src, u16* __restrict__ dst) {
  const size_t i = ((size_t)blockIdx.x * 256 + threadIdx.x) << 3;
  ushort4 lo, hi;
  if (i < (size_t)50000 * 768) {
    const float4 a = *(const float4*)(src + i);
    const float4 b = *(const float4*)(src + i + 4);
    lo.x = f2b(a.x); lo.y = f2b(a.y); lo.z = f2b(a.z); lo.w = f2b(a.w);
    hi.x = f2b(b.x); hi.y = f2b(b.y); hi.z = f2b(b.z); hi.w = f2b(b.w);
  } else {
    lo.x = lo.y = lo.z = lo.w = 0; hi.x = hi.y = hi.z = hi.w = 0;
  }
  *(ushort4*)(dst + i) = lo;
  *(ushort4*)(dst + i + 4) = hi;
}

// ---------------------------------------------------------------------------
// Phase 1: dense Q|K projection, 128x128 tile, global_load_lds(16B).
// QK2[m][j] = sum_k Xb[m][k] * W[j][k] + bias[j],  M=50048, N=1024, K=768.
// 1D grid 3128 with XCD-band swizzle: all 8 n-tiles of an m-tile map to the
// same XCD (blockIdx%8 heuristic) so each A tile is fetched by one L2 only.
// ---------------------------------------------------------------------------
__global__ __launch_bounds__(256)
void qk_gemm(const u16* __restrict__ Xb, const u16* __restrict__ W,
             const float* __restrict__ bias, u16* __restrict__ QK2) {
  __shared__ u16 As[128 * 32];
  __shared__ u16 Bs[128 * 32];
  const int g = blockIdx.x;            // 0..3127
  const int xcd = g & 7;
  const int lin = xcd * 391 + (g >> 3);
  const int n0 = (lin & 7) << 7;       // 8 n-tiles
  const int m0 = (lin >> 3) << 7;      // 391 m-tiles
  const int tid = threadIdx.x;
  const int wave = tid >> 6, lane = tid & 63;
  const int wm = wave >> 1, wn = wave & 1;
  const int quad = lane >> 4, l16 = lane & 15;

  const int r0 = (wave << 5) + (lane >> 2);
  const int cb = (lane & 3) << 3;
  const u16* gA = Xb + (size_t)(m0 + r0) * 768 + cb;
  const u16* gB = W  + (size_t)(n0 + r0) * 768 + cb;
  u16* lA = As + (wave << 10);
  u16* lB = Bs + (wave << 10);

  f32x4 acc[4][4];
  #pragma unroll
  for (int i = 0; i < 4; i++)
    #pragma unroll
    for (int j = 0; j < 4; j++) acc[i][j] = (f32x4){0.f, 0.f, 0.f, 0.f};

  for (int k0 = 0; k0 < 768; k0 += 32) {
    __syncthreads();
    gld_lds16(gA + k0,            lA);
    gld_lds16(gA + k0 + 16 * 768, lA + 512);
    gld_lds16(gB + k0,            lB);
    gld_lds16(gB + k0 + 16 * 768, lB + 512);
    __syncthreads();
    s16x8 af[4], bf[4];
    #pragma unroll
    for (int i = 0; i < 4; i++)
      af[i] = *(const s16x8*)(As + ((wm << 6) + (i << 4) + l16) * 32 + (quad << 3));
    #pragma unroll
    for (int j = 0; j < 4; j++)
      bf[j] = *(const s16x8*)(Bs + ((wn << 6) + (j << 4) + l16) * 32 + (quad << 3));
    #pragma unroll
    for (int i = 0; i < 4; i++)
      #pragma unroll
      for (int j = 0; j < 4; j++)
        acc[i][j] = mfma16(af[i], bf[j], acc[i][j]);
  }

  #pragma unroll
  for (int j = 0; j < 4; j++) {
    const int col = n0 + (wn << 6) + (j << 4) + l16;
    const float badd = bias[col];
    #pragma unroll
    for (int i = 0; i < 4; i++) {
      const int row = m0 + (wm << 6) + (i << 4) + (quad << 2);
      #pragma unroll
      for (int r = 0; r < 4; r++)
        QK2[(size_t)(row + r) * 1024 + col] = f2b(acc[i][j][r] + badd);
    }
  }
}

// ---------------------------------------------------------------------------
// Phase 2: per-(cell,head) S = QK^T -> softmax -> column sums w (no V at all).
// w_h[m] = (1/len) * sum_{l<len} P_h[l][m]
// ---------------------------------------------------------------------------
__global__ __launch_bounds__(256)
void attn2w(const u16* __restrict__ QK2, const int* __restrict__ cell_idx,
            const int* __restrict__ cell_len, float* __restrict__ w_g) {
  __shared__ int idx_s[64];
  __shared__ float Sf[64][66];

  const int c = blockIdx.x, h = blockIdx.y;
  const int tid = threadIdx.x;
  const int wave = tid >> 6, lane = tid & 63;
  const int quad = lane >> 4, l16 = lane & 15;

  int len = cell_len[c];
  len = (len < 1) ? 1 : ((len > 64) ? 64 : len);
  const int mt = (len + 15) >> 4;
  const float invLen = 1.0f / (float)len;

  if (tid < 64) idx_s[tid] = cell_idx[(c << 6) + tid];
  __syncthreads();

  // S = Q K^T (fragments straight from global; rows/cols >= len masked later)
  for (int item = wave; item < mt * mt; item += 4) {
    const int mq = item / mt, mk = item - mq * mt;
    const size_t qrow = (size_t)idx_s[(mq << 4) + l16] * 1024;
    const size_t krow = (size_t)idx_s[(mk << 4) + l16] * 1024;
    f32x4 s = {0.f, 0.f, 0.f, 0.f};
    #pragma unroll
    for (int ks = 0; ks < 2; ks++) {
      const s16x8 a = *(const s16x8*)(QK2 + qrow + (h << 6) + (ks << 5) + (quad << 3));
      const s16x8 b = *(const s16x8*)(QK2 + krow + 512 + (h << 6) + (ks << 5) + (quad << 3));
      s = mfma16(a, b, s);
    }
    const int col = (mk << 4) + l16, rb = (mq << 4) + (quad << 2);
    Sf[rb+0][col] = s[0]; Sf[rb+1][col] = s[1];
    Sf[rb+2][col] = s[2]; Sf[rb+3][col] = s[3];
  }
  __syncthreads();

  // softmax (4 threads/row, shuffle-combine), write normalized P back (fp32)
  {
    const int row = tid >> 2, sub = tid & 3, c0 = sub << 4;
    if (row < len) {
      float ev[16];
      float mx = -3e38f;
      #pragma unroll
      for (int t = 0; t < 16; t++) {
        const int cc = c0 + t;
        const float v = (cc < len) ? Sf[row][cc] : -3e38f;
        ev[t] = v; mx = fmaxf(mx, v);
      }
      mx = fmaxf(mx, __shfl_xor(mx, 1));
      mx = fmaxf(mx, __shfl_xor(mx, 2));
      float sum = 0.f;
      #pragma unroll
      for (int t = 0; t < 16; t++) {
        const int cc = c0 + t;
        const float e = (cc < len) ? __expf((ev[t] - mx) * 0.125f) : 0.f;
        ev[t] = e; sum += e;
      }
      sum += __shfl_xor(sum, 1);
      sum += __shfl_xor(sum, 2);
      const float inv = 1.0f / sum;
      #pragma unroll
      for (int t = 0; t < 16; t++) Sf[row][c0 + t] = ev[t] * inv;
    }
  }
  __syncthreads();

  // column sums -> w
  if (tid < 64) {
    float s = 0.f;
    if (tid < len)
      for (int l = 0; l < len; l++) s += Sf[l][tid];
    w_g[(size_t)((c << 3) + h) * 64 + tid] = s * invLen;
  }
}

// ---------------------------------------------------------------------------
// Phase 3: xbar[c][h][0:768] = sum_{m<len} w[c][h][m] * X[idx[c][m]][:]
// One block per cell; threads 0..191 each own 4 dims; all 8 heads together.
// ---------------------------------------------------------------------------
__global__ __launch_bounds__(256)
void xbar_k(const u16* __restrict__ Xb, const float* __restrict__ w_g,
            const int* __restrict__ cell_idx, const int* __restrict__ cell_len,
            u16* __restrict__ Xbar) {
  __shared__ int idx_s[64];
  __shared__ float wl[512];
  const int c = blockIdx.x;
  const int tid = threadIdx.x;

  int len = cell_len[c];
  len = (len < 1) ? 1 : ((len > 64) ? 64 : len);

  if (tid < 64) idx_s[tid] = cell_idx[(c << 6) + tid];
  wl[tid] = w_g[((size_t)c << 9) + tid];
  wl[tid + 256] = w_g[((size_t)c << 9) + tid + 256];
  __syncthreads();

  if (tid < 192) {
    const int d0 = tid << 2;
    float acc[8][4];
    #pragma unroll
    for (int h = 0; h < 8; h++)
      #pragma unroll
      for (int d = 0; d < 4; d++) acc[h][d] = 0.f;
    for (int m = 0; m < len; m++) {
      const ushort4 xv = *(const ushort4*)(Xb + (size_t)idx_s[m] * 768 + d0);
      const float x0 = b2f(xv.x), x1 = b2f(xv.y), x2 = b2f(xv.z), x3 = b2f(xv.w);
      #pragma unroll
      for (int h = 0; h < 8; h++) {
        const float wv = wl[(h << 6) + m];
        acc[h][0] += wv * x0; acc[h][1] += wv * x1;
        acc[h][2] += wv * x2; acc[h][3] += wv * x3;
      }
    }
    #pragma unroll
    for (int h = 0; h < 8; h++) {
      ushort4 o;
      o.x = f2b(acc[h][0]); o.y = f2b(acc[h][1]);
      o.z = f2b(acc[h][2]); o.w = f2b(acc[h][3]);
      *(ushort4*)(Xbar + (size_t)c * 6144 + (h * 768) + d0) = o;
    }
  }
}

// ---------------------------------------------------------------------------
// Phase 4: out[c][n] = sum_k Xbar[c][k]*Mh[n][k] + b2[n]; M=2048,N=256,K=6144
// 64x64 tiles, bf16 inputs via global_load_lds, fp32 out.
// ---------------------------------------------------------------------------
__global__ __launch_bounds__(256)
void gemm_final(const u16* __restrict__ A, const u16* __restrict__ B,
                const float* __restrict__ bias, float* __restrict__ out) {
  __shared__ u16 As[64 * 32];
  __shared__ u16 Bs[64 * 32];
  const int tid = threadIdx.x;
  const int wave = tid >> 6, lane = tid & 63;
  const int quad = lane >> 4, l16 = lane & 15;
  const int m0 = blockIdx.y << 6, n0 = blockIdx.x << 6;

  const int r = lane >> 2, c8 = (lane & 3) << 3;
  const u16* gA = A + (size_t)(m0 + (wave << 4) + r) * 6144 + c8;
  const u16* gB = B + (size_t)(n0 + (wave << 4) + r) * 6144 + c8;
  u16* lA = As + (wave << 9);
  u16* lB = Bs + (wave << 9);

  f32x4 acc[4] = {{0,0,0,0},{0,0,0,0},{0,0,0,0},{0,0,0,0}};
  for (int k0 = 0; k0 < 6144; k0 += 32) {
    __syncthreads();
    gld_lds16(gA + k0, lA);
    gld_lds16(gB + k0, lB);
    __syncthreads();
    const s16x8 a = *(const s16x8*)(As + ((wave << 4) + l16) * 32 + (quad << 3));
    #pragma unroll
    for (int j = 0; j < 4; j++) {
      const s16x8 b = *(const s16x8*)(Bs + ((j << 4) + l16) * 32 + (quad << 3));
      acc[j] = mfma16(a, b, acc[j]);
    }
  }
  const int row = m0 + (wave << 4) + (quad << 2);
  #pragma unroll
  for (int j = 0; j < 4; j++) {
    const int col = n0 + (j << 4) + l16;
    const float badd = bias[col];
    #pragma unroll
    for (int r2 = 0; r2 < 4; r2++)
      out[(size_t)(row + r2) * 256 + col] = acc[j][r2] + badd;
  }
}

// ---------------------------------------------------------------------------
// Fallback (round-0 proven path): fused per-cell attention, 1 block/cell.
// ---------------------------------------------------------------------------
template<int MT>
static __device__ __forceinline__ void heads_loop(
    const u16* __restrict__ Wqkv, const float* __restrict__ b_eff,
    u16 (*Xs)[776], u16 (*Qs)[72], u16 (*Ks)[72], u16 (*VTs)[72],
    u16 (*Psf)[72], float (*Sf)[65], float* pooled,
    const int len, const float invLen, const int tid) {
  const int wave = tid >> 6, lane = tid & 63;
  const int quad = lane >> 4, l16 = lane & 15;
  constexpr int LR = MT * 16;
  constexpr int KPV = (LR + 31) / 32;
  const float scale = 0.125f;

  for (int h = 0; h < 8; h++) {
    f32x4 acc[3][MT];
    #pragma unroll
    for (int it = 0; it < 3; it++)
      #pragma unroll
      for (int im = 0; im < MT; im++) acc[it][im] = (f32x4){0.f,0.f,0.f,0.f};
    int grow[3], jcol[3];
    #pragma unroll
    for (int it = 0; it < 3; it++) {
      const int j = ((wave * 3 + it) << 4) + l16;
      const int sec = j >> 6;
      grow[it] = (sec << 9) + (h << 6) + (j & 63);
      jcol[it] = j;
    }
    s16x8 bcur[3];
    #pragma unroll
    for (int it = 0; it < 3; it++)
      bcur[it] = *(const s16x8*)(Wqkv + (size_t)grow[it] * 768 + (quad << 3));
    for (int ks = 0; ks < 24; ks++) {
      s16x8 bnext[3];
      const int ksn = (ks < 23) ? (ks + 1) : 23;
      #pragma unroll
      for (int it = 0; it < 3; it++)
        bnext[it] = *(const s16x8*)(Wqkv + (size_t)grow[it] * 768 + (ksn << 5) + (quad << 3));
      s16x8 af[MT];
      #pragma unroll
      for (int im = 0; im < MT; im++)
        af[im] = *(const s16x8*)&Xs[(im << 4) + l16][(ks << 5) + (quad << 3)];
      #pragma unroll
      for (int it = 0; it < 3; it++)
        #pragma unroll
        for (int im = 0; im < MT; im++)
          acc[it][im] = mfma16(af[im], bcur[it], acc[it][im]);
      bcur[0] = bnext[0]; bcur[1] = bnext[1]; bcur[2] = bnext[2];
    }
    #pragma unroll
    for (int it = 0; it < 3; it++) {
      const float badd = b_eff[grow[it]];
      const int j = jcol[it];
      #pragma unroll
      for (int im = 0; im < MT; im++) {
        const int rb = (im << 4) + (quad << 2);
        if (j < 64) {
          #pragma unroll
          for (int r = 0; r < 4; r++) Qs[rb + r][j] = f2b(acc[it][im][r] + badd);
        } else if (j < 128) {
          #pragma unroll
          for (int r = 0; r < 4; r++) Ks[rb + r][j - 64] = f2b(acc[it][im][r] + badd);
        } else {
          ushort4 hv;
          hv.x = f2b(acc[it][im][0] + badd);
          hv.y = f2b(acc[it][im][1] + badd);
          hv.z = f2b(acc[it][im][2] + badd);
          hv.w = f2b(acc[it][im][3] + badd);
          *(ushort4*)&VTs[j - 128][rb] = hv;
        }
      }
    }
    __syncthreads();
    for (int item = wave; item < MT * MT; item += 4) {
      const int mq = item / MT, mk = item - mq * MT;
      f32x4 sacc = (f32x4){0.f,0.f,0.f,0.f};
      #pragma unroll
      for (int ks = 0; ks < 2; ks++) {
        const s16x8 a = *(const s16x8*)&Qs[(mq << 4) + l16][(ks << 5) + (quad << 3)];
        const s16x8 b = *(const s16x8*)&Ks[(mk << 4) + l16][(ks << 5) + (quad << 3)];
        sacc = mfma16(a, b, sacc);
      }
      const int col = (mk << 4) + l16;
      const int rb = (mq << 4) + (quad << 2);
      #pragma unroll
      for (int r = 0; r < 4; r++) Sf[rb + r][col] = sacc[r];
    }
    __syncthreads();
    if (tid < LR) {
      float mx = -1e30f;
      for (int m = 0; m < len; m++) mx = fmaxf(mx, Sf[tid][m]);
      float sum = 0.f;
      for (int m = 0; m < len; m++) {
        const float e = __expf((Sf[tid][m] - mx) * scale);
        Sf[tid][m] = e;
        sum += e;
      }
      const float inv = 1.0f / sum;
      for (int m = 0; m < len; m++) Psf[tid][m] = f2b(Sf[tid][m] * inv);
    }
    __syncthreads();
    for (int item = wave; item < MT * 4; item += 4) {
      const int mq = item >> 2, nd = item & 3;
      f32x4 cacc = (f32x4){0.f,0.f,0.f,0.f};
      #pragma unroll
      for (int ks = 0; ks < KPV; ks++) {
        const s16x8 a = *(const s16x8*)&Psf[(mq << 4) + l16][(ks << 5) + (quad << 3)];
        const s16x8 b = *(const s16x8*)&VTs[(nd << 4) + l16][(ks << 5) + (quad << 3)];
        cacc = mfma16(a, b, cacc);
      }
      const int col = (nd << 4) + l16;
      const int rb = (mq << 4) + (quad << 2);
      #pragma unroll
      for (int r = 0; r < 4; r++) Sf[rb + r][col] = cacc[r];
    }
    __syncthreads();
    if (tid < 64) {
      float s = 0.f;
      for (int l = 0; l < len; l++) s += Sf[l][tid];
      pooled[(h << 6) + tid] = s * invLen;
    }
    __syncthreads();
  }
}

__global__ __launch_bounds__(256, 1)
void cell_attn(const float* __restrict__ chunk, const u16* __restrict__ Wqkv,
               const float* __restrict__ b_eff, const int* __restrict__ cell_idx,
               const int* __restrict__ cell_len, float* __restrict__ pooled_g) {
  __shared__ u16 Xs[64][776];
  __shared__ u16 Qs[64][72];
  __shared__ u16 Ks[64][72];
  __shared__ u16 VTs[64][72];
  __shared__ u16 Psf[64][72];
  __shared__ float Sf[64][65];
  __shared__ float pooled[512];
  __shared__ int idx_s[64];

  const int c = blockIdx.x;
  const int tid = threadIdx.x;

  int len = cell_len[c];
  len = (len < 1) ? 1 : ((len > 64) ? 64 : len);
  const int mt = (len + 15) >> 4;
  const int Lr = mt << 4;
  const float invLen = 1.0f / (float)len;

  if (tid < 64) idx_s[tid] = cell_idx[(c << 6) + tid];
  __syncthreads();

  for (int i = tid; i < len * 192; i += 256) {
    const int r = i / 192;
    const int c4 = i - r * 192;
    const float4 f = *(const float4*)(chunk + (size_t)idx_s[r] * 768 + (c4 << 2));
    ushort4 hv; hv.x = f2b(f.x); hv.y = f2b(f.y); hv.z = f2b(f.z); hv.w = f2b(f.w);
    *(ushort4*)&Xs[r][c4 << 2] = hv;
  }
  const ushort4 z4 = {0, 0, 0, 0};
  for (int i = tid; i < (Lr - len) * 192; i += 256) {
    const int r = len + i / 192;
    const int c4 = i - (i / 192) * 192;
    *(ushort4*)&Xs[r][c4 << 2] = z4;
  }
  for (int i = tid; i < 1152; i += 256) *(ushort4*)(&Psf[0][0] + (i << 2)) = z4;
  for (int i = tid; i < 1152; i += 256) *(ushort4*)(&VTs[0][0] + (i << 2)) = z4;
  __syncthreads();

  switch (mt) {
    case 1: heads_loop<1>(Wqkv, b_eff, Xs, Qs, Ks, VTs, Psf, Sf, pooled, len, invLen, tid); break;
    case 2: heads_loop<2>(Wqkv, b_eff, Xs, Qs, Ks, VTs, Psf, Sf, pooled, len, invLen, tid); break;
    case 3: heads_loop<3>(Wqkv, b_eff, Xs, Qs, Ks, VTs, Psf, Sf, pooled, len, invLen, tid); break;
    default: heads_loop<4>(Wqkv, b_eff, Xs, Qs, Ks, VTs, Psf, Sf, pooled, len, invLen, tid); break;
  }

  for (int i = tid; i < 512; i += 256) pooled_g[((size_t)c << 9) + i] = pooled[i];
}

// ---------------------------------------------------------------------------
extern "C" void kernel_launch(void* const* d_in, const int* in_sizes, int n_in,
                              void* d_out, int out_size, void* d_ws, size_t ws_size,
                              hipStream_t stream) {
  const float* chunk  = (const float*)d_in[0];
  const float* Wq     = (const float*)d_in[1];
  const float* bq     = (const float*)d_in[2];
  const float* Wk     = (const float*)d_in[3];
  const float* bk     = (const float*)d_in[4];
  const float* Wv     = (const float*)d_in[5];
  const float* bv     = (const float*)d_in[6];
  const float* W_in   = (const float*)d_in[7];
  const float* b_in   = (const float*)d_in[8];
  const float* Wo     = (const float*)d_in[9];
  const float* bo     = (const float*)d_in[10];
  const float* Wout   = (const float*)d_in[11];
  const float* bout   = (const float*)d_in[12];
  const int* cell_idx = (const int*)d_in[13];
  const int* cell_len = (const int*)d_in[14];

  // workspace layout
  char* ws = (char*)d_ws;
  u16*   Wqkv   = (u16*)(ws + 0);              // [1536][768] bf16 (fast: rows 0-1023 only)
  float* b_eff  = (float*)(ws + 2359296);      // [1536]
  float* WfT    = (float*)(ws + 2365440);      // [512][256] fp32 (fallback)
  float* bfe    = (float*)(ws + 2889728);      // [256] Wout@bo+bout
  float* pooled = (float*)(ws + 2890752);      // [2048][512] fp32 (fallback)
  float* Wv_eff = (float*)(ws + 7085056);      // [512][768] fp32
  float* Wf     = (float*)(ws + 8657920);      // [256][512] fp32 = Wout@Wo
  float* b2     = (float*)(ws + 9182208);      // [256] final bias
  u16*   Mh     = (u16*)(ws + 9183232);        // [256][6144] bf16 (per-head blocks)
  float* w_g    = (float*)(ws + 12328960);     // [2048][8][64] fp32
  u16*   Xbar   = (u16*)(ws + 16523264);       // [2048][6144] bf16
  u16*   Xb     = (u16*)(ws + 41689088);       // [50048][768] bf16
  u16*   QK2    = (u16*)(ws + 118562816);      // [50048][1024] bf16
  const size_t FAST_NEED = 221061120ull;
  const bool fast = (ws_size >= FAST_NEED);

  dim3 blk(256);
  // fused projection weights: W{q,k}_eff = W_in[block] @ W{q,k}  (bf16)
  gemm_pre<0><<<dim3(12, 8), blk, 0, stream>>>(W_in,           Wq, (void*)Wqkv,            nullptr, 512, 768, 512, 512, 768, 768, 0, 0, 0);
  gemm_pre<0><<<dim3(12, 8), blk, 0, stream>>>(W_in + 512*512, Wk, (void*)(Wqkv + 512*768), nullptr, 512, 768, 512, 512, 768, 768, 0, 0, 0);
  bias_dot<<<dim3(2), blk, 0, stream>>>(W_in,            bq, b_in,        b_eff,        512, 512);
  bias_dot<<<dim3(2), blk, 0, stream>>>(W_in + 512*512,  bk, b_in + 512,  b_eff + 512,  512, 512);
  bias_dot<<<dim3(2), blk, 0, stream>>>(W_in + 1024*512, bv, b_in + 1024, b_eff + 1024, 512, 512);
  bias_dot<<<dim3(1), blk, 0, stream>>>(Wout, bo, bout, bfe, 256, 512);

  if (fast) {
    // Wv_eff fp32, Wf = Wout@Wo fp32
    gemm_pre<3><<<dim3(12, 8), blk, 0, stream>>>(W_in + 1024*512, Wv, (void*)Wv_eff, nullptr, 512, 768, 512, 512, 768, 768, 0, 0, 0);
    gemm_pre<3><<<dim3(8, 4), blk, 0, stream>>>(Wout, Wo, (void*)Wf, nullptr, 256, 512, 512, 512, 512, 512, 0, 0, 0);
    // b2 = Wf @ b_v_eff + bfe (stream-ordered after Wf and b_eff)
    bias_dot<<<dim3(1), blk, 0, stream>>>(Wf, b_eff + 1024, bfe, b2, 256, 512);
    // Mh[h] = Wf[:, h*64:(h+1)*64] @ Wv_eff[h*64:(h+1)*64, :]  (batched over z)
    gemm_pre<0><<<dim3(12, 4, 8), blk, 0, stream>>>(Wf, Wv_eff, (void*)Mh, nullptr,
        256, 768, 64, 512, 768, 6144, (size_t)64, (size_t)64*768, (size_t)768);
    convert_bf16<<<dim3(18768), blk, 0, stream>>>(chunk, Xb);
    qk_gemm<<<dim3(3128), blk, 0, stream>>>(Xb, Wqkv, b_eff, QK2);
    attn2w<<<dim3(2048, 8), blk, 0, stream>>>(QK2, cell_idx, cell_len, w_g);
    xbar_k<<<dim3(2048), blk, 0, stream>>>(Xb, w_g, cell_idx, cell_len, Xbar);
    gemm_final<<<dim3(4, 32), blk, 0, stream>>>(Xbar, Mh, b2, (float*)d_out);
  } else {
    gemm_pre<0><<<dim3(12, 8), blk, 0, stream>>>(W_in + 1024*512, Wv, (void*)(Wqkv + 1024*768), nullptr, 512, 768, 512, 512, 768, 768, 0, 0, 0);
    gemm_pre<1><<<dim3(8, 4), blk, 0, stream>>>(Wout, Wo, (void*)WfT, nullptr, 256, 512, 512, 512, 512, 256, 0, 0, 0);
    cell_attn<<<dim3(2048), blk, 0, stream>>>(chunk, Wqkv, b_eff, cell_idx, cell_len, pooled);
    gemm_pre<2><<<dim3(4, 32), blk, 0, stream>>>(pooled, WfT, d_out, bfe, 2048, 256, 512, 512, 256, 256, 0, 0, 0);
  }
}

// Round 4
// 659.722 us; speedup vs baseline: 1.1652x; 1.1652x over previous
//
#include <hip/hip_runtime.h>

typedef short s16x8 __attribute__((ext_vector_type(8)));
typedef float f32x4 __attribute__((ext_vector_type(4)));
typedef unsigned short u16;

static __device__ __forceinline__ f32x4 mfma16(s16x8 a, s16x8 b, f32x4 c) {
  return __builtin_amdgcn_mfma_f32_16x16x32_bf16(a, b, c, 0, 0, 0);
}

// fp32 -> bf16 round-to-nearest-even
static __device__ __forceinline__ u16 f2b(float f) {
  union { float f; unsigned int u; } v; v.f = f;
  unsigned int u = v.u;
  return (u16)((u + 0x7fffu + ((u >> 16) & 1u)) >> 16);
}
static __device__ __forceinline__ float b2f(u16 h) {
  union { float f; unsigned int u; } v; v.u = ((unsigned int)h) << 16;
  return v.f;
}

// async global->LDS, 16B per lane; LDS dest = wave-uniform base + lane*16
static __device__ __forceinline__ void gld_lds16(const void* g, void* l) {
  __builtin_amdgcn_global_load_lds(
      (const __attribute__((address_space(1))) void*)g,
      (__attribute__((address_space(3))) void*)l, 16, 0, 0);
}

// ---------------------------------------------------------------------------
// 64x64 GEMM tile from fp32 inputs (bf16-staged, fp32 acc).
// C[m][n] = sum_k A[m0+m][k]*B[k][n0+n]. MODE 0: bf16 store; MODE 3: fp32 store.
// Requires full 64x64 tile in-bounds, K%32==0.
// ---------------------------------------------------------------------------
template<int MODE>
static __device__ void gemm_tile(const float* __restrict__ A,
                                 const float* __restrict__ B,
                                 void* __restrict__ Cout,
                                 int m0, int n0, int K, int lda, int ldb, int ldc,
                                 u16 (*As)[40], u16 (*BsT)[40]) {
  const int tid = threadIdx.x;
  const int wave = tid >> 6, lane = tid & 63;
  const int quad = lane >> 4, l16 = lane & 15;
  f32x4 acc[4] = {{0,0,0,0},{0,0,0,0},{0,0,0,0},{0,0,0,0}};
  for (int k0 = 0; k0 < K; k0 += 32) {
    __syncthreads();
    { // stage A tile 64x32
      const int r = tid >> 2, cs = (tid & 3) << 3;
      const float* ap = A + (size_t)(m0 + r) * lda + k0 + cs;
      float4 v0 = *(const float4*)ap, v1 = *(const float4*)(ap + 4);
      As[r][cs+0] = f2b(v0.x); As[r][cs+1] = f2b(v0.y);
      As[r][cs+2] = f2b(v0.z); As[r][cs+3] = f2b(v0.w);
      As[r][cs+4] = f2b(v1.x); As[r][cs+5] = f2b(v1.y);
      As[r][cs+6] = f2b(v1.z); As[r][cs+7] = f2b(v1.w);
    }
    { // stage B tile 32x64 transposed -> BsT[n][k]
      const int kk = tid >> 3, ns = (tid & 7) << 3;
      const float* bp = B + (size_t)(k0 + kk) * ldb + n0 + ns;
      float4 v0 = *(const float4*)bp, v1 = *(const float4*)(bp + 4);
      BsT[ns+0][kk] = f2b(v0.x); BsT[ns+1][kk] = f2b(v0.y);
      BsT[ns+2][kk] = f2b(v0.z); BsT[ns+3][kk] = f2b(v0.w);
      BsT[ns+4][kk] = f2b(v1.x); BsT[ns+5][kk] = f2b(v1.y);
      BsT[ns+6][kk] = f2b(v1.z); BsT[ns+7][kk] = f2b(v1.w);
    }
    __syncthreads();
    const s16x8 af = *(const s16x8*)&As[(wave << 4) + l16][quad << 3];
    #pragma unroll
    for (int nt = 0; nt < 4; nt++) {
      const s16x8 bfr = *(const s16x8*)&BsT[(nt << 4) + l16][quad << 3];
      acc[nt] = mfma16(af, bfr, acc[nt]);
    }
  }
  const int mrow = m0 + (wave << 4) + (quad << 2);
  #pragma unroll
  for (int nt = 0; nt < 4; nt++) {
    const int n = n0 + (nt << 4) + l16;
    #pragma unroll
    for (int r = 0; r < 4; r++) {
      const float v = acc[nt][r];
      if (MODE == 0) ((u16*)Cout)[(size_t)(mrow + r) * ldc + n] = f2b(v);
      else           ((float*)Cout)[(size_t)(mrow + r) * ldc + n] = v;
    }
  }
}

// ---------------------------------------------------------------------------
// Launch 1: ALL precompute + fp32->bf16 conversion, one dispatch.
// blocks [0,96)    : Wq_eff  = W_in[0:512]    @ Wq  -> bf16 [512][768]
// blocks [96,192)  : Wk_eff  = W_in[512:1024] @ Wk  -> bf16 [512][768]
// blocks [192,288) : Wv_eff  = W_in[1024:]    @ Wv  -> fp32 [512][768]
// blocks [288,320) : Wf      = Wout @ Wo           -> fp32 [256][512]
// block  320       : bias chains: b_eff(q|k)[1024], b2[256]
// blocks [321,...) : chunk fp32 [50000][768] -> bf16 [50048][768] (pad 0)
// ---------------------------------------------------------------------------
__global__ __launch_bounds__(256)
void prep_all(const float* __restrict__ chunk,
              const float* __restrict__ Wq, const float* __restrict__ bq,
              const float* __restrict__ Wk, const float* __restrict__ bk,
              const float* __restrict__ Wv, const float* __restrict__ bv,
              const float* __restrict__ W_in, const float* __restrict__ b_in,
              const float* __restrict__ Wo, const float* __restrict__ bo,
              const float* __restrict__ Wout, const float* __restrict__ bout,
              u16* __restrict__ Wqkv, float* __restrict__ Wv_eff,
              float* __restrict__ Wf, float* __restrict__ b_eff,
              float* __restrict__ b2, u16* __restrict__ Xb) {
  __shared__ u16 As[64][40];
  __shared__ u16 BsT[64][40];
  __shared__ float t1s[512];
  __shared__ float t2s[512];
  const int b = blockIdx.x;
  const int tid = threadIdx.x;

  if (b < 96) {
    gemm_tile<0>(W_in, Wq, Wqkv, (b / 12) << 6, (b % 12) << 6, 512, 512, 768, 768, As, BsT);
  } else if (b < 192) {
    const int bb = b - 96;
    gemm_tile<0>(W_in + 512 * 512, Wk, Wqkv + 512 * 768,
                 (bb / 12) << 6, (bb % 12) << 6, 512, 512, 768, 768, As, BsT);
  } else if (b < 288) {
    const int bb = b - 192;
    gemm_tile<3>(W_in + 1024 * 512, Wv, Wv_eff,
                 (bb / 12) << 6, (bb % 12) << 6, 512, 512, 768, 768, As, BsT);
  } else if (b < 320) {
    const int bb = b - 288;
    gemm_tile<3>(Wout, Wo, Wf, (bb / 8) << 6, (bb % 8) << 6, 512, 512, 512, 512, As, BsT);
  } else if (b == 320) {
    // t1 = W_in_v @ bv + b_in_v  (512)
    for (int j = tid; j < 512; j += 256) {
      const float* ar = W_in + (size_t)(1024 + j) * 512;
      float acc = 0.f;
      for (int k = 0; k < 512; k += 4) {
        float4 w = *(const float4*)(ar + k);
        acc += w.x * bv[k] + w.y * bv[k+1] + w.z * bv[k+2] + w.w * bv[k+3];
      }
      t1s[j] = acc + b_in[1024 + j];
    }
    __syncthreads();
    // t2 = Wo @ t1 + bo  (512)
    for (int j = tid; j < 512; j += 256) {
      const float* ar = Wo + (size_t)j * 512;
      float acc = 0.f;
      for (int k = 0; k < 512; k += 4) {
        float4 w = *(const float4*)(ar + k);
        acc += w.x * t1s[k] + w.y * t1s[k+1] + w.z * t1s[k+2] + w.w * t1s[k+3];
      }
      t2s[j] = acc + bo[j];
    }
    __syncthreads();
    // b2 = Wout @ t2 + bout  (256)
    if (tid < 256) {
      const float* ar = Wout + (size_t)tid * 512;
      float acc = 0.f;
      for (int k = 0; k < 512; k += 4) {
        float4 w = *(const float4*)(ar + k);
        acc += w.x * t2s[k] + w.y * t2s[k+1] + w.z * t2s[k+2] + w.w * t2s[k+3];
      }
      b2[tid] = acc + bout[tid];
    }
    // b_eff_q / b_eff_k  (independent)
    for (int j = tid; j < 512; j += 256) {
      const float* aq = W_in + (size_t)j * 512;
      const float* ak = W_in + (size_t)(512 + j) * 512;
      float accq = 0.f, acck = 0.f;
      for (int k = 0; k < 512; k += 4) {
        float4 wq4 = *(const float4*)(aq + k);
        float4 wk4 = *(const float4*)(ak + k);
        accq += wq4.x * bq[k] + wq4.y * bq[k+1] + wq4.z * bq[k+2] + wq4.w * bq[k+3];
        acck += wk4.x * bk[k] + wk4.y * bk[k+1] + wk4.z * bk[k+2] + wk4.w * bk[k+3];
      }
      b_eff[j] = accq + b_in[j];
      b_eff[512 + j] = acck + b_in[512 + j];
    }
  } else {
    // conversion: 18768 blocks cover 50048*768 elements, 8 per thread
    const size_t i = (((size_t)(b - 321)) * 256 + tid) << 3;
    ushort4 lo, hi;
    if (i < (size_t)50000 * 768) {
      const float4 a = *(const float4*)(chunk + i);
      const float4 bb = *(const float4*)(chunk + i + 4);
      lo.x = f2b(a.x); lo.y = f2b(a.y); lo.z = f2b(a.z); lo.w = f2b(a.w);
      hi.x = f2b(bb.x); hi.y = f2b(bb.y); hi.z = f2b(bb.z); hi.w = f2b(bb.w);
    } else {
      lo.x = lo.y = lo.z = lo.w = 0; hi.x = hi.y = hi.z = hi.w = 0;
    }
    *(ushort4*)(Xb + i) = lo;
    *(ushort4*)(Xb + i + 4) = hi;
  }
}

// ---------------------------------------------------------------------------
// Launch 2: QK projection (3128 blocks, XCD-band swizzle) + Mh batched tiles
// (384 blocks), one dispatch.
// QK2[m][j] = sum_k Xb[m][k]*Wqkv[j][k] + b_eff[j], M=50048, N=1024, K=768.
// Mh[h]: [256][768] = Wf[:, h*64:(h+1)*64] @ Wv_eff[h*64:(h+1)*64, :]  (bf16)
// ---------------------------------------------------------------------------
__global__ __launch_bounds__(256)
void qk_mh(const u16* __restrict__ Xb, const u16* __restrict__ W,
           const float* __restrict__ bias, u16* __restrict__ QK2,
           const float* __restrict__ Wf, const float* __restrict__ Wv_eff,
           u16* __restrict__ Mh) {
  __shared__ char smem[16384];
  const int gb = blockIdx.x;
  const int tid = threadIdx.x;

  if (gb >= 3128) {
    const int bb = gb - 3128;           // [0,384)
    const int z = bb / 48, r = bb % 48;
    u16 (*As40)[40] = (u16(*)[40])smem;
    u16 (*Bs40)[40] = (u16(*)[40])(smem + 5120);
    gemm_tile<0>(Wf + z * 64, Wv_eff + (size_t)z * 64 * 768, Mh + z * 768,
                 (r / 12) << 6, (r % 12) << 6, 64, 512, 768, 6144, As40, Bs40);
    return;
  }

  u16* As = (u16*)smem;
  u16* Bs = (u16*)(smem + 8192);
  const int xcd = gb & 7;
  const int lin = xcd * 391 + (gb >> 3);
  const int n0 = (lin & 7) << 7;        // 8 n-tiles
  const int m0 = (lin >> 3) << 7;       // 391 m-tiles
  const int wave = tid >> 6, lane = tid & 63;
  const int wm = wave >> 1, wn = wave & 1;
  const int quad = lane >> 4, l16 = lane & 15;

  const int r0 = (wave << 5) + (lane >> 2);
  const int cb = (lane & 3) << 3;
  const u16* gA = Xb + (size_t)(m0 + r0) * 768 + cb;
  const u16* gB = W  + (size_t)(n0 + r0) * 768 + cb;
  u16* lA = As + (wave << 10);
  u16* lB = Bs + (wave << 10);

  f32x4 acc[4][4];
  #pragma unroll
  for (int i = 0; i < 4; i++)
    #pragma unroll
    for (int j = 0; j < 4; j++) acc[i][j] = (f32x4){0.f, 0.f, 0.f, 0.f};

  for (int k0 = 0; k0 < 768; k0 += 32) {
    __syncthreads();
    gld_lds16(gA + k0,            lA);
    gld_lds16(gA + k0 + 16 * 768, lA + 512);
    gld_lds16(gB + k0,            lB);
    gld_lds16(gB + k0 + 16 * 768, lB + 512);
    __syncthreads();
    s16x8 af[4], bf[4];
    #pragma unroll
    for (int i = 0; i < 4; i++)
      af[i] = *(const s16x8*)(As + ((wm << 6) + (i << 4) + l16) * 32 + (quad << 3));
    #pragma unroll
    for (int j = 0; j < 4; j++)
      bf[j] = *(const s16x8*)(Bs + ((wn << 6) + (j << 4) + l16) * 32 + (quad << 3));
    #pragma unroll
    for (int i = 0; i < 4; i++)
      #pragma unroll
      for (int j = 0; j < 4; j++)
        acc[i][j] = mfma16(af[i], bf[j], acc[i][j]);
  }

  #pragma unroll
  for (int j = 0; j < 4; j++) {
    const int col = n0 + (wn << 6) + (j << 4) + l16;
    const float badd = bias[col];
    #pragma unroll
    for (int i = 0; i < 4; i++) {
      const int row = m0 + (wm << 6) + (i << 4) + (quad << 2);
      #pragma unroll
      for (int r = 0; r < 4; r++)
        QK2[(size_t)(row + r) * 1024 + col] = f2b(acc[i][j][r] + badd);
    }
  }
}

// ---------------------------------------------------------------------------
// Launch 3: per-cell: for each of 8 heads S=QK^T -> softmax -> column sums w,
// then xbar[h] = sum_m w_h[m]*X[idx[m]] for all heads -> Xbar bf16 [c][6144].
// ---------------------------------------------------------------------------
__global__ __launch_bounds__(256)
void attn_pool(const u16* __restrict__ QK2, const u16* __restrict__ Xb,
               const int* __restrict__ cell_idx, const int* __restrict__ cell_len,
               u16* __restrict__ Xbar) {
  __shared__ int idx_s[64];
  __shared__ float Sf[64][66];
  __shared__ float wl[512];

  const int c = blockIdx.x;
  const int tid = threadIdx.x;
  const int wave = tid >> 6, lane = tid & 63;
  const int quad = lane >> 4, l16 = lane & 15;

  int len = cell_len[c];
  len = (len < 1) ? 1 : ((len > 64) ? 64 : len);
  const int mt = (len + 15) >> 4;
  const float invLen = 1.0f / (float)len;

  if (tid < 64) idx_s[tid] = cell_idx[(c << 6) + tid];
  __syncthreads();

  for (int h = 0; h < 8; h++) {
    // S = Q K^T (fragments straight from global)
    for (int item = wave; item < mt * mt; item += 4) {
      const int mq = item / mt, mk = item - mq * mt;
      const size_t qrow = (size_t)idx_s[(mq << 4) + l16] * 1024;
      const size_t krow = (size_t)idx_s[(mk << 4) + l16] * 1024;
      f32x4 s = {0.f, 0.f, 0.f, 0.f};
      #pragma unroll
      for (int ks = 0; ks < 2; ks++) {
        const s16x8 a = *(const s16x8*)(QK2 + qrow + (h << 6) + (ks << 5) + (quad << 3));
        const s16x8 b = *(const s16x8*)(QK2 + krow + 512 + (h << 6) + (ks << 5) + (quad << 3));
        s = mfma16(a, b, s);
      }
      const int col = (mk << 4) + l16, rb = (mq << 4) + (quad << 2);
      Sf[rb+0][col] = s[0]; Sf[rb+1][col] = s[1];
      Sf[rb+2][col] = s[2]; Sf[rb+3][col] = s[3];
    }
    __syncthreads();

    // softmax: 4 threads/row, shuffle-combine; normalized P written back fp32
    {
      const int row = tid >> 2, sub = tid & 3, c0 = sub << 4;
      if (row < len) {
        float ev[16];
        float mx = -3e38f;
        #pragma unroll
        for (int t = 0; t < 16; t++) {
          const int cc = c0 + t;
          const float v = (cc < len) ? Sf[row][cc] : -3e38f;
          ev[t] = v; mx = fmaxf(mx, v);
        }
        mx = fmaxf(mx, __shfl_xor(mx, 1));
        mx = fmaxf(mx, __shfl_xor(mx, 2));
        float sum = 0.f;
        #pragma unroll
        for (int t = 0; t < 16; t++) {
          const int cc = c0 + t;
          const float e = (cc < len) ? __expf((ev[t] - mx) * 0.125f) : 0.f;
          ev[t] = e; sum += e;
        }
        sum += __shfl_xor(sum, 1);
        sum += __shfl_xor(sum, 2);
        const float inv = 1.0f / sum;
        #pragma unroll
        for (int t = 0; t < 16; t++) Sf[row][c0 + t] = ev[t] * inv;
      }
    }
    __syncthreads();

    // column sums -> w
    if (tid < 64) {
      float s = 0.f;
      if (tid < len)
        for (int l = 0; l < len; l++) s += Sf[l][tid];
      wl[(h << 6) + tid] = s * invLen;
    }
    __syncthreads();
  }

  // xbar: threads 0..191 each own 4 dims, all 8 heads
  if (tid < 192) {
    const int d0 = tid << 2;
    float acc[8][4];
    #pragma unroll
    for (int h = 0; h < 8; h++)
      #pragma unroll
      for (int d = 0; d < 4; d++) acc[h][d] = 0.f;
    for (int m = 0; m < len; m++) {
      const ushort4 xv = *(const ushort4*)(Xb + (size_t)idx_s[m] * 768 + d0);
      const float x0 = b2f(xv.x), x1 = b2f(xv.y), x2 = b2f(xv.z), x3 = b2f(xv.w);
      #pragma unroll
      for (int h = 0; h < 8; h++) {
        const float wv = wl[(h << 6) + m];
        acc[h][0] += wv * x0; acc[h][1] += wv * x1;
        acc[h][2] += wv * x2; acc[h][3] += wv * x3;
      }
    }
    #pragma unroll
    for (int h = 0; h < 8; h++) {
      ushort4 o;
      o.x = f2b(acc[h][0]); o.y = f2b(acc[h][1]);
      o.z = f2b(acc[h][2]); o.w = f2b(acc[h][3]);
      *(ushort4*)(Xbar + (size_t)c * 6144 + (h * 768) + d0) = o;
    }
  }
}

// ---------------------------------------------------------------------------
// Launch 4: out[c][n] = sum_k Xbar[c][k]*Mh[n][k] + b2[n]; M=2048,N=256,K=6144
// ---------------------------------------------------------------------------
__global__ __launch_bounds__(256)
void gemm_final(const u16* __restrict__ A, const u16* __restrict__ B,
                const float* __restrict__ bias, float* __restrict__ out) {
  __shared__ u16 As[64 * 32];
  __shared__ u16 Bs[64 * 32];
  const int tid = threadIdx.x;
  const int wave = tid >> 6, lane = tid & 63;
  const int quad = lane >> 4, l16 = lane & 15;
  const int m0 = blockIdx.y << 6, n0 = blockIdx.x << 6;

  const int r = lane >> 2, c8 = (lane & 3) << 3;
  const u16* gA = A + (size_t)(m0 + (wave << 4) + r) * 6144 + c8;
  const u16* gB = B + (size_t)(n0 + (wave << 4) + r) * 6144 + c8;
  u16* lA = As + (wave << 9);
  u16* lB = Bs + (wave << 9);

  f32x4 acc[4] = {{0,0,0,0},{0,0,0,0},{0,0,0,0},{0,0,0,0}};
  for (int k0 = 0; k0 < 6144; k0 += 32) {
    __syncthreads();
    gld_lds16(gA + k0, lA);
    gld_lds16(gB + k0, lB);
    __syncthreads();
    const s16x8 a = *(const s16x8*)(As + ((wave << 4) + l16) * 32 + (quad << 3));
    #pragma unroll
    for (int j = 0; j < 4; j++) {
      const s16x8 b = *(const s16x8*)(Bs + ((j << 4) + l16) * 32 + (quad << 3));
      acc[j] = mfma16(a, b, acc[j]);
    }
  }
  const int row = m0 + (wave << 4) + (quad << 2);
  #pragma unroll
  for (int j = 0; j < 4; j++) {
    const int col = n0 + (j << 4) + l16;
    const float badd = bias[col];
    #pragma unroll
    for (int r2 = 0; r2 < 4; r2++)
      out[(size_t)(row + r2) * 256 + col] = acc[j][r2] + badd;
  }
}

// ---------------------------------------------------------------------------
extern "C" void kernel_launch(void* const* d_in, const int* in_sizes, int n_in,
                              void* d_out, int out_size, void* d_ws, size_t ws_size,
                              hipStream_t stream) {
  const float* chunk  = (const float*)d_in[0];
  const float* Wq     = (const float*)d_in[1];
  const float* bq     = (const float*)d_in[2];
  const float* Wk     = (const float*)d_in[3];
  const float* bk     = (const float*)d_in[4];
  const float* Wv     = (const float*)d_in[5];
  const float* bv     = (const float*)d_in[6];
  const float* W_in   = (const float*)d_in[7];
  const float* b_in   = (const float*)d_in[8];
  const float* Wo     = (const float*)d_in[9];
  const float* bo     = (const float*)d_in[10];
  const float* Wout   = (const float*)d_in[11];
  const float* bout   = (const float*)d_in[12];
  const int* cell_idx = (const int*)d_in[13];
  const int* cell_len = (const int*)d_in[14];

  // workspace layout (~211 MB; ws_size >= 237 MB verified rounds 2-3)
  char* ws = (char*)d_ws;
  u16*   Wqkv   = (u16*)(ws + 0);              // [1024][768] bf16 (q|k fused)
  float* Wv_eff = (float*)(ws + 1572864);      // [512][768] fp32
  float* Wf     = (float*)(ws + 3145728);      // [256][512] fp32 = Wout@Wo
  float* b_eff  = (float*)(ws + 3670016);      // [1024] fused q|k bias
  float* b2     = (float*)(ws + 3674112);      // [256] final bias
  u16*   Mh     = (u16*)(ws + 3675136);        // [256][6144] bf16
  u16*   Xbar   = (u16*)(ws + 6820864);        // [2048][6144] bf16
  u16*   Xb     = (u16*)(ws + 31986688);       // [50048][768] bf16
  u16*   QK2    = (u16*)(ws + 108860416);      // [50048][1024] bf16

  dim3 blk(256);
  prep_all<<<dim3(19089), blk, 0, stream>>>(chunk, Wq, bq, Wk, bk, Wv, bv,
      W_in, b_in, Wo, bo, Wout, bout, Wqkv, Wv_eff, Wf, b_eff, b2, Xb);
  qk_mh<<<dim3(3512), blk, 0, stream>>>(Xb, Wqkv, b_eff, QK2, Wf, Wv_eff, Mh);
  attn_pool<<<dim3(2048), blk, 0, stream>>>(QK2, Xb, cell_idx, cell_len, Xbar);
  gemm_final<<<dim3(4, 32), blk, 0, stream>>>(Xbar, Mh, b2, (float*)d_out);
}

// Round 5
// 596.141 us; speedup vs baseline: 1.2895x; 1.1067x over previous
//
#include <hip/hip_runtime.h>

typedef short s16x8 __attribute__((ext_vector_type(8)));
typedef float f32x4 __attribute__((ext_vector_type(4)));
typedef unsigned short u16;

static __device__ __forceinline__ f32x4 mfma16(s16x8 a, s16x8 b, f32x4 c) {
  return __builtin_amdgcn_mfma_f32_16x16x32_bf16(a, b, c, 0, 0, 0);
}

// fp32 -> bf16 round-to-nearest-even
static __device__ __forceinline__ u16 f2b(float f) {
  union { float f; unsigned int u; } v; v.f = f;
  unsigned int u = v.u;
  return (u16)((u + 0x7fffu + ((u >> 16) & 1u)) >> 16);
}
static __device__ __forceinline__ float b2f(u16 h) {
  union { float f; unsigned int u; } v; v.u = ((unsigned int)h) << 16;
  return v.f;
}

// async global->LDS, 16B per lane; LDS dest = wave-uniform base + lane*16
static __device__ __forceinline__ void gld_lds16(const void* g, void* l) {
  __builtin_amdgcn_global_load_lds(
      (const __attribute__((address_space(1))) void*)g,
      (__attribute__((address_space(3))) void*)l, 16, 0, 0);
}

// ---------------------------------------------------------------------------
// 64x64 GEMM tile from fp32 inputs (bf16-staged, fp32 acc).
// MODE 0: bf16 store; MODE 3: fp32 store. Full tile in-bounds, K%32==0.
// ---------------------------------------------------------------------------
template<int MODE>
static __device__ void gemm_tile(const float* __restrict__ A,
                                 const float* __restrict__ B,
                                 void* __restrict__ Cout,
                                 int m0, int n0, int K, int lda, int ldb, int ldc,
                                 u16 (*As)[40], u16 (*BsT)[40]) {
  const int tid = threadIdx.x;
  const int wave = tid >> 6, lane = tid & 63;
  const int quad = lane >> 4, l16 = lane & 15;
  f32x4 acc[4] = {{0,0,0,0},{0,0,0,0},{0,0,0,0},{0,0,0,0}};
  for (int k0 = 0; k0 < K; k0 += 32) {
    __syncthreads();
    { // stage A tile 64x32
      const int r = tid >> 2, cs = (tid & 3) << 3;
      const float* ap = A + (size_t)(m0 + r) * lda + k0 + cs;
      float4 v0 = *(const float4*)ap, v1 = *(const float4*)(ap + 4);
      As[r][cs+0] = f2b(v0.x); As[r][cs+1] = f2b(v0.y);
      As[r][cs+2] = f2b(v0.z); As[r][cs+3] = f2b(v0.w);
      As[r][cs+4] = f2b(v1.x); As[r][cs+5] = f2b(v1.y);
      As[r][cs+6] = f2b(v1.z); As[r][cs+7] = f2b(v1.w);
    }
    { // stage B tile 32x64 transposed -> BsT[n][k]
      const int kk = tid >> 3, ns = (tid & 7) << 3;
      const float* bp = B + (size_t)(k0 + kk) * ldb + n0 + ns;
      float4 v0 = *(const float4*)bp, v1 = *(const float4*)(bp + 4);
      BsT[ns+0][kk] = f2b(v0.x); BsT[ns+1][kk] = f2b(v0.y);
      BsT[ns+2][kk] = f2b(v0.z); BsT[ns+3][kk] = f2b(v0.w);
      BsT[ns+4][kk] = f2b(v1.x); BsT[ns+5][kk] = f2b(v1.y);
      BsT[ns+6][kk] = f2b(v1.z); BsT[ns+7][kk] = f2b(v1.w);
    }
    __syncthreads();
    const s16x8 af = *(const s16x8*)&As[(wave << 4) + l16][quad << 3];
    #pragma unroll
    for (int nt = 0; nt < 4; nt++) {
      const s16x8 bfr = *(const s16x8*)&BsT[(nt << 4) + l16][quad << 3];
      acc[nt] = mfma16(af, bfr, acc[nt]);
    }
  }
  const int mrow = m0 + (wave << 4) + (quad << 2);
  #pragma unroll
  for (int nt = 0; nt < 4; nt++) {
    const int n = n0 + (nt << 4) + l16;
    #pragma unroll
    for (int r = 0; r < 4; r++) {
      const float v = acc[nt][r];
      if (MODE == 0) ((u16*)Cout)[(size_t)(mrow + r) * ldc + n] = f2b(v);
      else           ((float*)Cout)[(size_t)(mrow + r) * ldc + n] = v;
    }
  }
}

// ---------------------------------------------------------------------------
// Launch 1: ALL precompute + fp32->bf16 conversion (grid-stride), one dispatch.
// blocks [0,96)    : Wq_eff bf16   [96,192): Wk_eff bf16   [192,288): Wv_eff f32
// blocks [288,320) : Wf = Wout@Wo f32      block 320: bias chains
// blocks [321,2369): grid-stride conversion chunk fp32 -> Xb bf16 (pad rows 0)
// ---------------------------------------------------------------------------
__global__ __launch_bounds__(256)
void prep_all(const float* __restrict__ chunk,
              const float* __restrict__ Wq, const float* __restrict__ bq,
              const float* __restrict__ Wk, const float* __restrict__ bk,
              const float* __restrict__ Wv, const float* __restrict__ bv,
              const float* __restrict__ W_in, const float* __restrict__ b_in,
              const float* __restrict__ Wo, const float* __restrict__ bo,
              const float* __restrict__ Wout, const float* __restrict__ bout,
              u16* __restrict__ Wqkv, float* __restrict__ Wv_eff,
              float* __restrict__ Wf, float* __restrict__ b_eff,
              float* __restrict__ b2, u16* __restrict__ Xb) {
  __shared__ u16 As[64][40];
  __shared__ u16 BsT[64][40];
  __shared__ float t1s[512];
  __shared__ float t2s[512];
  const int b = blockIdx.x;
  const int tid = threadIdx.x;

  if (b < 96) {
    gemm_tile<0>(W_in, Wq, Wqkv, (b / 12) << 6, (b % 12) << 6, 512, 512, 768, 768, As, BsT);
  } else if (b < 192) {
    const int bb = b - 96;
    gemm_tile<0>(W_in + 512 * 512, Wk, Wqkv + 512 * 768,
                 (bb / 12) << 6, (bb % 12) << 6, 512, 512, 768, 768, As, BsT);
  } else if (b < 288) {
    const int bb = b - 192;
    gemm_tile<3>(W_in + 1024 * 512, Wv, Wv_eff,
                 (bb / 12) << 6, (bb % 12) << 6, 512, 512, 768, 768, As, BsT);
  } else if (b < 320) {
    const int bb = b - 288;
    gemm_tile<3>(Wout, Wo, Wf, (bb / 8) << 6, (bb % 8) << 6, 512, 512, 512, 512, As, BsT);
  } else if (b == 320) {
    // t1 = W_in_v @ bv + b_in_v
    for (int j = tid; j < 512; j += 256) {
      const float* ar = W_in + (size_t)(1024 + j) * 512;
      float acc = 0.f;
      for (int k = 0; k < 512; k += 4) {
        float4 w = *(const float4*)(ar + k);
        acc += w.x * bv[k] + w.y * bv[k+1] + w.z * bv[k+2] + w.w * bv[k+3];
      }
      t1s[j] = acc + b_in[1024 + j];
    }
    __syncthreads();
    // t2 = Wo @ t1 + bo
    for (int j = tid; j < 512; j += 256) {
      const float* ar = Wo + (size_t)j * 512;
      float acc = 0.f;
      for (int k = 0; k < 512; k += 4) {
        float4 w = *(const float4*)(ar + k);
        acc += w.x * t1s[k] + w.y * t1s[k+1] + w.z * t1s[k+2] + w.w * t1s[k+3];
      }
      t2s[j] = acc + bo[j];
    }
    __syncthreads();
    // b2 = Wout @ t2 + bout
    if (tid < 256) {
      const float* ar = Wout + (size_t)tid * 512;
      float acc = 0.f;
      for (int k = 0; k < 512; k += 4) {
        float4 w = *(const float4*)(ar + k);
        acc += w.x * t2s[k] + w.y * t2s[k+1] + w.z * t2s[k+2] + w.w * t2s[k+3];
      }
      b2[tid] = acc + bout[tid];
    }
    // b_eff_q / b_eff_k
    for (int j = tid; j < 512; j += 256) {
      const float* aq = W_in + (size_t)j * 512;
      const float* ak = W_in + (size_t)(512 + j) * 512;
      float accq = 0.f, acck = 0.f;
      for (int k = 0; k < 512; k += 4) {
        float4 wq4 = *(const float4*)(aq + k);
        float4 wk4 = *(const float4*)(ak + k);
        accq += wq4.x * bq[k] + wq4.y * bq[k+1] + wq4.z * bq[k+2] + wq4.w * bq[k+3];
        acck += wk4.x * bk[k] + wk4.y * bk[k+1] + wk4.z * bk[k+2] + wk4.w * bk[k+3];
      }
      b_eff[j] = accq + b_in[j];
      b_eff[512 + j] = acck + b_in[512 + j];
    }
  } else {
    // grid-stride conversion: 2048 blocks cover 50048*768/8 = 4804608 groups
    const size_t stride = 2048 * 256;
    for (size_t g = (size_t)(b - 321) * 256 + tid; g < 4804608ull; g += stride) {
      const size_t i = g << 3;
      ushort4 lo, hi;
      if (i < (size_t)50000 * 768) {
        const float4 a = *(const float4*)(chunk + i);
        const float4 bb = *(const float4*)(chunk + i + 4);
        lo.x = f2b(a.x); lo.y = f2b(a.y); lo.z = f2b(a.z); lo.w = f2b(a.w);
        hi.x = f2b(bb.x); hi.y = f2b(bb.y); hi.z = f2b(bb.z); hi.w = f2b(bb.w);
      } else {
        lo.x = lo.y = lo.z = lo.w = 0; hi.x = hi.y = hi.z = hi.w = 0;
      }
      *(ushort4*)(Xb + i) = lo;
      *(ushort4*)(Xb + i + 4) = hi;
    }
  }
}

// ---------------------------------------------------------------------------
// Launch 2: QK projection (3128 blocks, XCD-band swizzle) + Mh tiles (384).
// ---------------------------------------------------------------------------
__global__ __launch_bounds__(256)
void qk_mh(const u16* __restrict__ Xb, const u16* __restrict__ W,
           const float* __restrict__ bias, u16* __restrict__ QK2,
           const float* __restrict__ Wf, const float* __restrict__ Wv_eff,
           u16* __restrict__ Mh) {
  __shared__ char smem[16384];
  const int gb = blockIdx.x;
  const int tid = threadIdx.x;

  if (gb >= 3128) {
    const int bb = gb - 3128;           // [0,384)
    const int z = bb / 48, r = bb % 48;
    u16 (*As40)[40] = (u16(*)[40])smem;
    u16 (*Bs40)[40] = (u16(*)[40])(smem + 5120);
    gemm_tile<0>(Wf + z * 64, Wv_eff + (size_t)z * 64 * 768, Mh + z * 768,
                 (r / 12) << 6, (r % 12) << 6, 64, 512, 768, 6144, As40, Bs40);
    return;
  }

  u16* As = (u16*)smem;
  u16* Bs = (u16*)(smem + 8192);
  const int xcd = gb & 7;
  const int lin = xcd * 391 + (gb >> 3);
  const int n0 = (lin & 7) << 7;
  const int m0 = (lin >> 3) << 7;
  const int wave = tid >> 6, lane = tid & 63;
  const int wm = wave >> 1, wn = wave & 1;
  const int quad = lane >> 4, l16 = lane & 15;

  const int r0 = (wave << 5) + (lane >> 2);
  const int cb = (lane & 3) << 3;
  const u16* gA = Xb + (size_t)(m0 + r0) * 768 + cb;
  const u16* gB = W  + (size_t)(n0 + r0) * 768 + cb;
  u16* lA = As + (wave << 10);
  u16* lB = Bs + (wave << 10);

  f32x4 acc[4][4];
  #pragma unroll
  for (int i = 0; i < 4; i++)
    #pragma unroll
    for (int j = 0; j < 4; j++) acc[i][j] = (f32x4){0.f, 0.f, 0.f, 0.f};

  for (int k0 = 0; k0 < 768; k0 += 32) {
    __syncthreads();
    gld_lds16(gA + k0,            lA);
    gld_lds16(gA + k0 + 16 * 768, lA + 512);
    gld_lds16(gB + k0,            lB);
    gld_lds16(gB + k0 + 16 * 768, lB + 512);
    __syncthreads();
    s16x8 af[4], bf[4];
    #pragma unroll
    for (int i = 0; i < 4; i++)
      af[i] = *(const s16x8*)(As + ((wm << 6) + (i << 4) + l16) * 32 + (quad << 3));
    #pragma unroll
    for (int j = 0; j < 4; j++)
      bf[j] = *(const s16x8*)(Bs + ((wn << 6) + (j << 4) + l16) * 32 + (quad << 3));
    #pragma unroll
    for (int i = 0; i < 4; i++)
      #pragma unroll
      for (int j = 0; j < 4; j++)
        acc[i][j] = mfma16(af[i], bf[j], acc[i][j]);
  }

  #pragma unroll
  for (int j = 0; j < 4; j++) {
    const int col = n0 + (wn << 6) + (j << 4) + l16;
    const float badd = bias[col];
    #pragma unroll
    for (int i = 0; i < 4; i++) {
      const int row = m0 + (wm << 6) + (i << 4) + (quad << 2);
      #pragma unroll
      for (int r = 0; r < 4; r++)
        QK2[(size_t)(row + r) * 1024 + col] = f2b(acc[i][j][r] + badd);
    }
  }
}

// ---------------------------------------------------------------------------
// Per-wave, per-head: S = QK^T (MFMA, frags from global), softmax + column
// sums entirely in registers (16-lane shfl for rows, xor 16/32 for columns).
// Writes w_h (prob column-sums / len) to wl[h*64 + m]. No barriers.
// ---------------------------------------------------------------------------
template<int MT>
static __device__ __forceinline__ void head_sw(
    const u16* __restrict__ QK2, const int* __restrict__ idx_s,
    float* __restrict__ wl, const int h, const int len, const float invLen,
    const int quad, const int l16) {
  f32x4 sacc[MT][MT];
  #pragma unroll
  for (int mq = 0; mq < MT; mq++)
    #pragma unroll
    for (int mk = 0; mk < MT; mk++) sacc[mq][mk] = (f32x4){0.f, 0.f, 0.f, 0.f};

  #pragma unroll
  for (int ks = 0; ks < 2; ks++) {
    s16x8 qa[MT], kb[MT];
    #pragma unroll
    for (int mq = 0; mq < MT; mq++)
      qa[mq] = *(const s16x8*)(QK2 + (size_t)idx_s[(mq << 4) + l16] * 1024
                               + (h << 6) + (ks << 5) + (quad << 3));
    #pragma unroll
    for (int mk = 0; mk < MT; mk++)
      kb[mk] = *(const s16x8*)(QK2 + (size_t)idx_s[(mk << 4) + l16] * 1024 + 512
                               + (h << 6) + (ks << 5) + (quad << 3));
    #pragma unroll
    for (int mq = 0; mq < MT; mq++)
      #pragma unroll
      for (int mk = 0; mk < MT; mk++)
        sacc[mq][mk] = mfma16(qa[mq], kb[mk], sacc[mq][mk]);
  }

  // mask columns m >= len (column index = mk*16 + l16, uniform per lane)
  #pragma unroll
  for (int mk = 0; mk < MT; mk++) {
    if (((mk << 4) + l16) >= len) {
      #pragma unroll
      for (int mq = 0; mq < MT; mq++)
        sacc[mq][mk] = (f32x4){-3e38f, -3e38f, -3e38f, -3e38f};
    }
  }

  // softmax per row (row = mq*16 + quad*4 + r): reduce across mk regs + 16 lanes
  #pragma unroll
  for (int mq = 0; mq < MT; mq++) {
    #pragma unroll
    for (int r = 0; r < 4; r++) {
      float mx = sacc[mq][0][r];
      #pragma unroll
      for (int mk = 1; mk < MT; mk++) mx = fmaxf(mx, sacc[mq][mk][r]);
      mx = fmaxf(mx, __shfl_xor(mx, 1));
      mx = fmaxf(mx, __shfl_xor(mx, 2));
      mx = fmaxf(mx, __shfl_xor(mx, 4));
      mx = fmaxf(mx, __shfl_xor(mx, 8));
      float sum = 0.f;
      #pragma unroll
      for (int mk = 0; mk < MT; mk++) {
        const float e = __expf((sacc[mq][mk][r] - mx) * 0.125f);
        sacc[mq][mk][r] = e; sum += e;
      }
      sum += __shfl_xor(sum, 1);
      sum += __shfl_xor(sum, 2);
      sum += __shfl_xor(sum, 4);
      sum += __shfl_xor(sum, 8);
      const float inv = 1.0f / sum;
      #pragma unroll
      for (int mk = 0; mk < MT; mk++) sacc[mq][mk][r] *= inv;
    }
  }

  // column sums over valid rows -> w[m]; combine quads via xor 16/32
  #pragma unroll
  for (int mk = 0; mk < MT; mk++) {
    float cs = 0.f;
    #pragma unroll
    for (int mq = 0; mq < MT; mq++)
      #pragma unroll
      for (int r = 0; r < 4; r++)
        cs += (((mq << 4) + (quad << 2) + r) < len) ? sacc[mq][mk][r] : 0.f;
    cs += __shfl_xor(cs, 16);
    cs += __shfl_xor(cs, 32);
    if (quad == 0) wl[(h << 6) + (mk << 4) + l16] = cs * invLen;
  }
}

// ---------------------------------------------------------------------------
// Launch 3: per-cell block; wave w handles heads 2w, 2w+1 (no barriers), then
// one sync and a cooperative xbar gather -> Xbar bf16 [c][6144].
// ---------------------------------------------------------------------------
__global__ __launch_bounds__(256)
void attn_pool(const u16* __restrict__ QK2, const u16* __restrict__ Xb,
               const int* __restrict__ cell_idx, const int* __restrict__ cell_len,
               u16* __restrict__ Xbar) {
  __shared__ int idx_s[64];
  __shared__ float wl[512];

  const int c = blockIdx.x;
  const int tid = threadIdx.x;
  const int wave = tid >> 6, lane = tid & 63;
  const int quad = lane >> 4, l16 = lane & 15;

  int len = cell_len[c];
  len = (len < 1) ? 1 : ((len > 64) ? 64 : len);
  const int mt = (len + 15) >> 4;
  const float invLen = 1.0f / (float)len;

  if (tid < 64) idx_s[tid] = cell_idx[(c << 6) + tid];
  __syncthreads();

  const int h0 = wave << 1;
  switch (mt) {
    case 1:
      head_sw<1>(QK2, idx_s, wl, h0,     len, invLen, quad, l16);
      head_sw<1>(QK2, idx_s, wl, h0 + 1, len, invLen, quad, l16);
      break;
    case 2:
      head_sw<2>(QK2, idx_s, wl, h0,     len, invLen, quad, l16);
      head_sw<2>(QK2, idx_s, wl, h0 + 1, len, invLen, quad, l16);
      break;
    case 3:
      head_sw<3>(QK2, idx_s, wl, h0,     len, invLen, quad, l16);
      head_sw<3>(QK2, idx_s, wl, h0 + 1, len, invLen, quad, l16);
      break;
    default:
      head_sw<4>(QK2, idx_s, wl, h0,     len, invLen, quad, l16);
      head_sw<4>(QK2, idx_s, wl, h0 + 1, len, invLen, quad, l16);
      break;
  }
  __syncthreads();

  // xbar: threads 0..191 each own 4 dims, all 8 heads
  if (tid < 192) {
    const int d0 = tid << 2;
    float acc[8][4];
    #pragma unroll
    for (int h = 0; h < 8; h++)
      #pragma unroll
      for (int d = 0; d < 4; d++) acc[h][d] = 0.f;
    for (int m = 0; m < len; m++) {
      const ushort4 xv = *(const ushort4*)(Xb + (size_t)idx_s[m] * 768 + d0);
      const float x0 = b2f(xv.x), x1 = b2f(xv.y), x2 = b2f(xv.z), x3 = b2f(xv.w);
      #pragma unroll
      for (int h = 0; h < 8; h++) {
        const float wv = wl[(h << 6) + m];
        acc[h][0] += wv * x0; acc[h][1] += wv * x1;
        acc[h][2] += wv * x2; acc[h][3] += wv * x3;
      }
    }
    #pragma unroll
    for (int h = 0; h < 8; h++) {
      ushort4 o;
      o.x = f2b(acc[h][0]); o.y = f2b(acc[h][1]);
      o.z = f2b(acc[h][2]); o.w = f2b(acc[h][3]);
      *(ushort4*)(Xbar + (size_t)c * 6144 + (h * 768) + d0) = o;
    }
  }
}

// ---------------------------------------------------------------------------
// Launch 4: K-split final GEMM. partial[z][c][n] = sum_{k in z-slice} ...
// grid (4, 32, 6): z over K slices of 1024.
// ---------------------------------------------------------------------------
__global__ __launch_bounds__(256)
void gemm_final_ks(const u16* __restrict__ A, const u16* __restrict__ B,
                   float* __restrict__ partial) {
  __shared__ u16 As[64 * 32];
  __shared__ u16 Bs[64 * 32];
  const int tid = threadIdx.x;
  const int wave = tid >> 6, lane = tid & 63;
  const int quad = lane >> 4, l16 = lane & 15;
  const int m0 = blockIdx.y << 6, n0 = blockIdx.x << 6;
  const int z = blockIdx.z;

  const int r = lane >> 2, c8 = (lane & 3) << 3;
  const u16* gA = A + (size_t)(m0 + (wave << 4) + r) * 6144 + (z << 10) + c8;
  const u16* gB = B + (size_t)(n0 + (wave << 4) + r) * 6144 + (z << 10) + c8;
  u16* lA = As + (wave << 9);
  u16* lB = Bs + (wave << 9);

  f32x4 acc[4] = {{0,0,0,0},{0,0,0,0},{0,0,0,0},{0,0,0,0}};
  for (int k0 = 0; k0 < 1024; k0 += 32) {
    __syncthreads();
    gld_lds16(gA + k0, lA);
    gld_lds16(gB + k0, lB);
    __syncthreads();
    const s16x8 a = *(const s16x8*)(As + ((wave << 4) + l16) * 32 + (quad << 3));
    #pragma unroll
    for (int j = 0; j < 4; j++) {
      const s16x8 b = *(const s16x8*)(Bs + ((j << 4) + l16) * 32 + (quad << 3));
      acc[j] = mfma16(a, b, acc[j]);
    }
  }
  float* pz = partial + (size_t)z * 524288;
  const int row = m0 + (wave << 4) + (quad << 2);
  #pragma unroll
  for (int j = 0; j < 4; j++) {
    const int col = n0 + (j << 4) + l16;
    #pragma unroll
    for (int r2 = 0; r2 < 4; r2++)
      pz[(size_t)(row + r2) * 256 + col] = acc[j][r2];
  }
}

// Launch 5: out = sum_z partial[z] + b2
__global__ __launch_bounds__(256)
void reduce_out(const float* __restrict__ partial, const float* __restrict__ b2,
                float* __restrict__ out) {
  const size_t base = ((size_t)blockIdx.x * 256 + threadIdx.x) << 2;
  float4 s = *(const float4*)(partial + base);
  #pragma unroll
  for (int z = 1; z < 6; z++) {
    const float4 p = *(const float4*)(partial + (size_t)z * 524288 + base);
    s.x += p.x; s.y += p.y; s.z += p.z; s.w += p.w;
  }
  const int col = (int)(base & 255);
  const float4 bb = *(const float4*)(b2 + col);
  s.x += bb.x; s.y += bb.y; s.z += bb.z; s.w += bb.w;
  *(float4*)(out + base) = s;
}

// ---------------------------------------------------------------------------
extern "C" void kernel_launch(void* const* d_in, const int* in_sizes, int n_in,
                              void* d_out, int out_size, void* d_ws, size_t ws_size,
                              hipStream_t stream) {
  const float* chunk  = (const float*)d_in[0];
  const float* Wq     = (const float*)d_in[1];
  const float* bq     = (const float*)d_in[2];
  const float* Wk     = (const float*)d_in[3];
  const float* bk     = (const float*)d_in[4];
  const float* Wv     = (const float*)d_in[5];
  const float* bv     = (const float*)d_in[6];
  const float* W_in   = (const float*)d_in[7];
  const float* b_in   = (const float*)d_in[8];
  const float* Wo     = (const float*)d_in[9];
  const float* bo     = (const float*)d_in[10];
  const float* Wout   = (const float*)d_in[11];
  const float* bout   = (const float*)d_in[12];
  const int* cell_idx = (const int*)d_in[13];
  const int* cell_len = (const int*)d_in[14];

  // workspace layout (~224 MB; ws_size >= 237 MB verified)
  char* ws = (char*)d_ws;
  u16*   Wqkv    = (u16*)(ws + 0);              // [1024][768] bf16 (q|k fused)
  float* Wv_eff  = (float*)(ws + 1572864);      // [512][768] fp32
  float* Wf      = (float*)(ws + 3145728);      // [256][512] fp32 = Wout@Wo
  float* b_eff   = (float*)(ws + 3670016);      // [1024]
  float* b2      = (float*)(ws + 3674112);      // [256]
  u16*   Mh      = (u16*)(ws + 3675136);        // [256][6144] bf16
  u16*   Xbar    = (u16*)(ws + 6820864);        // [2048][6144] bf16
  u16*   Xb      = (u16*)(ws + 31986688);       // [50048][768] bf16
  u16*   QK2     = (u16*)(ws + 108860416);      // [50048][1024] bf16
  float* partial = (float*)(ws + 211358720);    // [6][2048][256] fp32

  dim3 blk(256);
  prep_all<<<dim3(2369), blk, 0, stream>>>(chunk, Wq, bq, Wk, bk, Wv, bv,
      W_in, b_in, Wo, bo, Wout, bout, Wqkv, Wv_eff, Wf, b_eff, b2, Xb);
  qk_mh<<<dim3(3512), blk, 0, stream>>>(Xb, Wqkv, b_eff, QK2, Wf, Wv_eff, Mh);
  attn_pool<<<dim3(2048), blk, 0, stream>>>(QK2, Xb, cell_idx, cell_len, Xbar);
  gemm_final_ks<<<dim3(4, 32, 6), blk, 0, stream>>>(Xbar, Mh, partial);
  reduce_out<<<dim3(512), blk, 0, stream>>>(partial, b2, (float*)d_out);
}